// Round 15
// baseline (346.504 us; speedup 1.0000x reference)
//
#include <hip/hip_runtime.h>
#include <stdint.h>

typedef unsigned short u16;
typedef uint32_t u32;
typedef short s16x8 __attribute__((ext_vector_type(8)));
typedef float fx16 __attribute__((ext_vector_type(16)));

#define B_   256
#define H_   1024
#define BH_  (B_ * H_)                  // 262144
#define WPE  ((size_t)2 * 4096 * 2048)  // W pack elems
#define XPE  ((size_t)15 * BH_)
#define HPE  ((size_t)32 * BH_)
#define NT   32                         // K-steps (BK=64)

struct Stage { int node[8]; int par[8]; int layer[8]; int cnt; };

__device__ __forceinline__ u16 bf16_rn(float x) {
    union { float f; u32 u; } v; v.f = x;
    return (u16)((v.u + 0x7FFFu + ((v.u >> 16) & 1u)) >> 16);
}
__device__ __forceinline__ float sigf(float x) {
    return __builtin_amdgcn_rcpf(1.0f + __expf(-x));
}
__device__ __forceinline__ float tanh_f(float x) {
    return 1.0f - 2.0f * __builtin_amdgcn_rcpf(1.0f + __expf(2.0f * x));
}

// ---------------------------------------------------------------------------
// Pack W into MFMA-B fragment order, bf16. Chunk w = ((layer*4+gate)*32+cg)*128+k16;
// lane l -> W[gate*1024+cg*32+(l&31)][k16*16+(l>>5)*8+e].
// ---------------------------------------------------------------------------
__global__ __launch_bounds__(256)
void pack_weights(const float* __restrict__ Wih, const float* __restrict__ Whh,
                  u16* __restrict__ wp)
{
    const int gt = blockIdx.x * 256 + threadIdx.x;
    const int w = gt >> 6, lane = gt & 63;
    const int k16 = w & 127, cg = (w >> 7) & 31, gate = (w >> 12) & 3, layer = w >> 14;
    const int row = gate * 1024 + cg * 32 + (lane & 31);
    const int k = k16 * 16 + (lane >> 5) * 8;
    const float* src = (k < 1024)
        ? Wih + ((size_t)layer * 4096 + row) * 1024 + k
        : Whh + ((size_t)layer * 4096 + row) * 1024 + (k - 1024);
    const float4 v0 = *(const float4*)src;
    const float4 v1 = *(const float4*)(src + 4);
    const float a[8] = {v0.x, v0.y, v0.z, v0.w, v1.x, v1.y, v1.z, v1.w};
    union { u16 s[8]; uint4 v; } hi;
    #pragma unroll
    for (int e = 0; e < 8; ++e) hi.s[e] = bf16_rn(a[e]);
    *(uint4*)(wp + (size_t)w * 512 + (size_t)lane * 8) = hi.v;
}

__global__ __launch_bounds__(256)
void pack_x(const float* __restrict__ input, const float* __restrict__ bridge,
            u16* __restrict__ xp)
{
    const int gt = blockIdx.x * 256 + threadIdx.x;
    const int w = gt >> 6, lane = gt & 63;
    const int k16 = w & 63, btile = (w >> 6) & 7, n1 = w >> 9;
    const int b = btile * 32 + (lane & 31);
    const int k = k16 * 16 + (lane >> 5) * 8;
    const float* src = (k < 512)
        ? input  + ((size_t)n1 * 256 + b) * 512 + k
        : bridge + ((size_t)n1 * 256 + b) * 512 + (k - 512);
    const float4 v0 = *(const float4*)src;
    const float4 v1 = *(const float4*)(src + 4);
    const float a[8] = {v0.x, v0.y, v0.z, v0.w, v1.x, v1.y, v1.z, v1.w};
    union { u16 s[8]; uint4 v; } hi;
    #pragma unroll
    for (int e = 0; e < 8; ++e) hi.s[e] = bf16_rn(a[e]);
    *(uint4*)(xp + (size_t)w * 512 + (size_t)lane * 8) = hi.v;
}

__global__ __launch_bounds__(256)
void bias_sum_k(const float* __restrict__ bih, const float* __restrict__ bhh,
                float* __restrict__ bs)
{
    const int i = blockIdx.x * 256 + threadIdx.x;
    if (i < 8192) bs[i] = bih[i] + bhh[i];
}

// ---------------------------------------------------------------------------
// Fused cell, BARRIER-FREE register-direct K-loop. Block = 256 thr (4 waves),
// tile M=128 x N=128 (4 gates x 32 hh); wave (mw,nw) -> 64 rows x 64 cols
// (2x2 32x32 frags). Per BK=64 step per wave: 8 A + 8 W global_load_dwordx4
// straight to VGPRs (packed layouts are contiguous streams per wave) +
// 16 MFMA. NO LDS, NO __syncthreads in the loop -- compiler pipelines loads
// of step t+1 under MFMAs of step t; 8 waves/CU TLP hides the rest.
// LDS (37 KB) only used by the fused epilogue overlay.
// bid map: mblk = bid >= grid/2 -> both mblk halves of one (cell,hhblk) land
// on the same CU (bid distance 256 for cnt=8) -> W stream L1-shared.
// par==0 cells skip seg1 (parent h == 0 adds exact zeros).
// ---------------------------------------------------------------------------
__global__ __launch_bounds__(256, 2)
void cell_fused(const u16* __restrict__ wp, const u16* __restrict__ xp,
                u16* __restrict__ hp, float* __restrict__ c_buf,
                const float* __restrict__ bsum, float* __restrict__ out,
                Stage st)
{
    __shared__ __align__(16) char SMEM[37376];
    float* gbuf = (float*)SMEM;          // [64][129] f32 (epilogue)
    u16*   tbuf = (u16*)(SMEM + 33024);  // [64][33] u16 (epilogue)

    const int bid  = blockIdx.x;
    const int half = gridDim.x >> 1;
    const int mblk = (bid >= half) ? 1 : 0;
    const int v    = bid - mblk * half;
    const int hhblk = 4 * (v & 7) + ((v >> 3) & 3);   // 0..31, XCD-stable
    const int cell  = v >> 5;
    const int node = st.node[cell], par = st.par[cell], layer = st.layer[cell];
    const int tid = threadIdx.x, wv = tid >> 6, lane = tid & 63;
    const int mw = wv >> 1, nw = wv & 1;
    const int l8 = lane * 8;

    // A row-stream bases for this wave (two 32-row chunks), per segment
    const u16 *A0, *A1;
    if (layer == 0) {
        A0 = xp + (size_t)(node - 1) * BH_;
        A1 = hp + (size_t)(par * 2 + 0) * BH_;
    } else {
        A0 = hp + (size_t)(node * 2 + 0) * BH_;
        A1 = hp + (size_t)(par * 2 + 1) * BH_;
    }
    const u16* a0s[2]; const u16* a1s[2];
    #pragma unroll
    for (int m = 0; m < 2; ++m) {
        const size_t bt = (size_t)(mblk * 4 + mw * 2 + m) * 64 * 512 + l8;
        a0s[m] = A0 + bt;
        a1s[m] = A1 + bt;
    }
    // W col-stream bases (two gates)
    const u16* wns[2];
    #pragma unroll
    for (int n = 0; n < 2; ++n)
        wns[n] = wp + (size_t)((layer * 4 + (nw * 2 + n)) * 32 + hhblk) * 65536 + l8;

    const int nsteps = (par == 0) ? (NT / 2) : NT;

    fx16 acc[2][2];
    #pragma unroll
    for (int m = 0; m < 2; ++m)
        #pragma unroll
        for (int n = 0; n < 2; ++n)
            #pragma unroll
            for (int r = 0; r < 16; ++r) acc[m][n][r] = 0.0f;

    #pragma unroll 2
    for (int t = 0; t < nsteps; ++t) {
        const int seg1 = (t >= 16);
        const size_t ka = (size_t)((t & 15) * 4) * 512;   // A: within-segment k16
        const size_t kw = (size_t)(t * 4) * 512;          // W: global k16

        s16x8 a[2][4], w[2][4];
        #pragma unroll
        for (int m = 0; m < 2; ++m) {
            const u16* ap = (seg1 ? a1s[m] : a0s[m]) + ka;
            #pragma unroll
            for (int kk = 0; kk < 4; ++kk)
                a[m][kk] = *(const s16x8*)(ap + (size_t)kk * 512);
        }
        #pragma unroll
        for (int n = 0; n < 2; ++n) {
            const u16* wpn = wns[n] + kw;
            #pragma unroll
            for (int kk = 0; kk < 4; ++kk)
                w[n][kk] = *(const s16x8*)(wpn + (size_t)kk * 512);
        }
        #pragma unroll
        for (int kk = 0; kk < 4; ++kk)
            #pragma unroll
            for (int m = 0; m < 2; ++m)
                #pragma unroll
                for (int n = 0; n < 2; ++n)
                    acc[m][n] = __builtin_amdgcn_mfma_f32_32x32x16_bf16(
                        a[m][kk], w[n][kk], acc[m][n], 0, 0, 0);
    }

    // ---- fused epilogue, two row-passes (p = mw of producing waves)
    const int hhl  = tid & 31;
    const int colg = hhblk * 32 + hhl;
    float bs4[4];
    #pragma unroll
    for (int g = 0; g < 4; ++g)
        bs4[g] = bsum[layer * 4096 + g * 1024 + colg];

    const float* cpar = c_buf + (size_t)(par * 2 + layer) * BH_ + colg;
    float*       cnew = c_buf + (size_t)(node * 2 + layer) * BH_ + colg;
    float*       outp = out + (size_t)(node - 1) * BH_ + colg;
    u16*         hpn  = hp + (size_t)(node * 2 + layer) * BH_;

    #pragma unroll
    for (int p = 0; p < 2; ++p) {
        __syncthreads();
        if (mw == p) {
            // C/D layout: col = lane&31, row = (r&3)+8*(r>>2)+4*(lane>>5)
            #pragma unroll
            for (int m = 0; m < 2; ++m) {
                #pragma unroll
                for (int n = 0; n < 2; ++n) {
                    const int col = (nw * 2 + n) * 32 + (lane & 31);
                    #pragma unroll
                    for (int r = 0; r < 16; ++r) {
                        const int row_l = m * 32 + 4 * (lane >> 5)
                                        + (r & 3) + 8 * (r >> 2);
                        gbuf[row_l * 129 + col] = acc[m][n][r];
                    }
                }
            }
        }
        __syncthreads();
        // gate math: 8 rows/thread-group x 32 hh
        #pragma unroll
        for (int e = 0; e < 8; ++e) {
            const int row_l = e * 8 + (tid >> 5);
            const size_t grow = (size_t)(mblk * 128 + p * 64 + row_l) * 1024;
            const float gi = gbuf[row_l * 129 + 0  * 32 + hhl] + bs4[0];
            const float gf = gbuf[row_l * 129 + 1  * 32 + hhl] + bs4[1];
            const float gg = gbuf[row_l * 129 + 2  * 32 + hhl] + bs4[2];
            const float go = gbuf[row_l * 129 + 3  * 32 + hhl] + bs4[3];
            const float cp = cpar[grow];
            const float cn = sigf(gf) * cp + sigf(gi) * tanh_f(gg);
            const float hn = sigf(go) * tanh_f(cn);
            cnew[grow] = cn;
            if (layer == 1) outp[grow] = hn;
            tbuf[row_l * 33 + hhl] = bf16_rn(hn);
        }
        __syncthreads();
        // pack h: 4 chunks (j = btl-in-pass, q = k16 half), one per wave
        {
            const int j = wv >> 1, q = wv & 1;
            const int bt   = mblk * 4 + p * 2 + j;
            const int k16h = hhblk * 2 + q;
            union { u16 s[8]; uint4 v; } pk;
            #pragma unroll
            for (int e = 0; e < 8; ++e)
                pk.s[e] = tbuf[(j * 32 + (lane & 31)) * 33
                               + q * 16 + (lane >> 5) * 8 + e];
            *(uint4*)(hpn + ((size_t)bt * 64 + k16h) * 512 + lane * 8) = pk.v;
        }
    }
}

// ---------------------------------------------------------------------------
extern "C" void kernel_launch(void* const* d_in, const int* in_sizes, int n_in,
                              void* d_out, int out_size, void* d_ws, size_t ws_size,
                              hipStream_t stream)
{
    const float* input  = (const float*)d_in[0];
    const float* bridge = (const float*)d_in[1];
    const float* Wih    = (const float*)d_in[2];
    const float* Whh    = (const float*)d_in[3];
    const float* bih    = (const float*)d_in[4];
    const float* bhh    = (const float*)d_in[5];
    float* out = (float*)d_out;

    u16* wp = (u16*)d_ws;
    u16* xp = wp + WPE;
    u16* hp = xp + XPE;
    float* c_buf = (float*)(hp + HPE);
    float* bsum  = c_buf + HPE;

    hipMemsetAsync(hp, 0, (size_t)2 * BH_ * sizeof(u16), stream);
    hipMemsetAsync(c_buf, 0, (size_t)2 * BH_ * sizeof(float), stream);

    bias_sum_k<<<32, 256, 0, stream>>>(bih, bhh, bsum);
    pack_weights<<<8192, 256, 0, stream>>>(Wih, Whh, wp);
    pack_x<<<1920, 256, 0, stream>>>(input, bridge, xp);

    // Wavefront schedule: stage T = cells (node,layer) with depth(node)+layer==T
    static const Stage stages[7] = {
        { {1},                      {0},                      {0},                      1 },
        { {1,2,5,8},                {0,1,1,1},                {1,0,0,0},                4 },
        { {2,5,8,3,6,9,12},         {1,1,1,2,5,8,8},          {1,1,1,0,0,0,0},          7 },
        { {3,6,9,12,4,7,10,13},     {2,5,8,8,3,6,9,12},       {1,1,1,1,0,0,0,0},        8 },
        { {4,7,10,13,11,14},        {3,6,9,12,10,13},         {1,1,1,1,0,0},            6 },
        { {11,14,15},               {10,13,14},               {1,1,0},                  3 },
        { {15},                     {14},                     {1},                      1 },
    };

    for (int s = 0; s < 7; ++s) {
        cell_fused<<<dim3(stages[s].cnt * 64), 256, 0, stream>>>(
            wp, xp, hp, c_buf, bsum, out, stages[s]);
    }
}

// Round 16
// 254.739 us; speedup vs baseline: 1.3602x; 1.3602x over previous
//
#include <hip/hip_runtime.h>
#include <stdint.h>

typedef unsigned short u16;
typedef uint32_t u32;
typedef short s16x8 __attribute__((ext_vector_type(8)));
typedef float fx16 __attribute__((ext_vector_type(16)));

#define B_   256
#define H_   1024
#define BH_  (B_ * H_)                  // 262144
#define WPE  ((size_t)2 * 4096 * 2048)  // W pack elems
#define XPE  ((size_t)15 * BH_)
#define HPE  ((size_t)32 * BH_)
#define NT   32                         // K-steps (BK=64)

struct Stage { int node[8]; int par[8]; int layer[8]; int cnt; };

__device__ __forceinline__ u16 bf16_rn(float x) {
    union { float f; u32 u; } v; v.f = x;
    return (u16)((v.u + 0x7FFFu + ((v.u >> 16) & 1u)) >> 16);
}
__device__ __forceinline__ float sigf(float x) {
    return __builtin_amdgcn_rcpf(1.0f + __expf(-x));
}
__device__ __forceinline__ float tanh_f(float x) {
    return 1.0f - 2.0f * __builtin_amdgcn_rcpf(1.0f + __expf(2.0f * x));
}

// ---------------------------------------------------------------------------
// Pack W into MFMA-B fragment order, bf16. Chunk w = ((layer*4+gate)*32+cg)*128+k16;
// lane l -> W[gate*1024+cg*32+(l&31)][k16*16+(l>>5)*8+e].
// ---------------------------------------------------------------------------
__global__ __launch_bounds__(256)
void pack_weights(const float* __restrict__ Wih, const float* __restrict__ Whh,
                  u16* __restrict__ wp)
{
    const int gt = blockIdx.x * 256 + threadIdx.x;
    const int w = gt >> 6, lane = gt & 63;
    const int k16 = w & 127, cg = (w >> 7) & 31, gate = (w >> 12) & 3, layer = w >> 14;
    const int row = gate * 1024 + cg * 32 + (lane & 31);
    const int k = k16 * 16 + (lane >> 5) * 8;
    const float* src = (k < 1024)
        ? Wih + ((size_t)layer * 4096 + row) * 1024 + k
        : Whh + ((size_t)layer * 4096 + row) * 1024 + (k - 1024);
    const float4 v0 = *(const float4*)src;
    const float4 v1 = *(const float4*)(src + 4);
    const float a[8] = {v0.x, v0.y, v0.z, v0.w, v1.x, v1.y, v1.z, v1.w};
    union { u16 s[8]; uint4 v; } hi;
    #pragma unroll
    for (int e = 0; e < 8; ++e) hi.s[e] = bf16_rn(a[e]);
    *(uint4*)(wp + (size_t)w * 512 + (size_t)lane * 8) = hi.v;
}

__global__ __launch_bounds__(256)
void pack_x(const float* __restrict__ input, const float* __restrict__ bridge,
            u16* __restrict__ xp)
{
    const int gt = blockIdx.x * 256 + threadIdx.x;
    const int w = gt >> 6, lane = gt & 63;
    const int k16 = w & 63, btile = (w >> 6) & 7, n1 = w >> 9;
    const int b = btile * 32 + (lane & 31);
    const int k = k16 * 16 + (lane >> 5) * 8;
    const float* src = (k < 512)
        ? input  + ((size_t)n1 * 256 + b) * 512 + k
        : bridge + ((size_t)n1 * 256 + b) * 512 + (k - 512);
    const float4 v0 = *(const float4*)src;
    const float4 v1 = *(const float4*)(src + 4);
    const float a[8] = {v0.x, v0.y, v0.z, v0.w, v1.x, v1.y, v1.z, v1.w};
    union { u16 s[8]; uint4 v; } hi;
    #pragma unroll
    for (int e = 0; e < 8; ++e) hi.s[e] = bf16_rn(a[e]);
    *(uint4*)(xp + (size_t)w * 512 + (size_t)lane * 8) = hi.v;
}

__global__ __launch_bounds__(256)
void bias_sum_k(const float* __restrict__ bih, const float* __restrict__ bhh,
                float* __restrict__ bs)
{
    const int i = blockIdx.x * 256 + threadIdx.x;
    if (i < 8192) bs[i] = bih[i] + bhh[i];
}

// ---------------------------------------------------------------------------
// Fused cell: LDS double-buffer + COUNTED vmcnt (never drains to 0 mid-loop).
// Block = 256 thr (4 waves), tile M=128 x N=128 (4 gates x 32 hh).
// LDS 64 KB: buf b = {A 16KB | W 16KB} at b*32KB -> 2 blocks/CU.
// Loop: vmcnt(8) [retire S(t), leave S(t+1)'s 8 in flight] -> s_barrier ->
// COMPUTE(t) -> s_barrier -> issue S(t+2) into buf[t&1]. Stage t+1's loads
// get a full compute-step of in-flight time; no wait-to-zero until the end.
// par==0 cells skip seg1 (parent h == 0). 64 blocks/cell.
// ---------------------------------------------------------------------------
__global__ __launch_bounds__(256, 2)
void cell_fused(const u16* __restrict__ wp, const u16* __restrict__ xp,
                u16* __restrict__ hp, float* __restrict__ c_buf,
                const float* __restrict__ bsum, float* __restrict__ out,
                Stage st)
{
    __shared__ __align__(16) char SMEM[65536];
    u16*   BUF  = (u16*)SMEM;            // buf b: A at b*16384, W at +8192 elems
    float* gbuf = (float*)SMEM;          // [64][129] f32 (epilogue overlay)
    u16*   tbuf = (u16*)(SMEM + 33024);  // [64][33] u16 (epilogue overlay)

    const int u = blockIdx.x;
    const int hhblk = 4 * (u & 7) + ((u >> 3) & 3);   // 0..31, XCD-stable
    const int v = u >> 5;
    const int cnt = st.cnt;
    const int cell = v % cnt;
    const int mblk = v / cnt;                          // 0..1
    const int node = st.node[cell], par = st.par[cell], layer = st.layer[cell];
    const int tid = threadIdx.x, wv = tid >> 6, lane = tid & 63;
    const int mw = wv >> 1, nw = wv & 1;
    const int tg = tid >> 6;                           // 0..3
    const int tl8 = (tid & 63) * 8;

    // A segment bases (seg0 = K 0..1023, seg1 = K 1024..2047)
    const u16 *A0, *A1;
    if (layer == 0) {
        A0 = xp + (size_t)(node - 1) * BH_;
        A1 = hp + (size_t)(par * 2 + 0) * BH_;
    } else {
        A0 = hp + (size_t)(node * 2 + 0) * BH_;
        A1 = hp + (size_t)(par * 2 + 1) * BH_;
    }
    size_t wsrc[4];
    #pragma unroll
    for (int g = 0; g < 4; ++g)
        wsrc[g] = ((size_t)((layer * 4 + g) * 32 + hhblk) * 128 + tg) * 512
                + (size_t)tl8;

    // per-thread per STAGE: 4 A-instr + 4 W-instr = 8 vmcnt events
    #define STAGE(T, BB) do {                                                  \
        const u16* As_ = ((T) < 16) ? A0 : A1;                                 \
        const int k16_ = ((T) & 15) * 4 + tg;                                  \
        _Pragma("unroll")                                                      \
        for (int i_ = 0; i_ < 4; ++i_) {                                       \
            __builtin_amdgcn_global_load_lds(                                  \
                (const __attribute__((address_space(1))) void*)                \
                    (As_ + ((size_t)(mblk * 4 + i_) * 64 + k16_) * 512 + tl8), \
                (__attribute__((address_space(3))) void*)                      \
                    (BUF + (BB) * 16384 + (i_ * 4 + tg) * 512 + tl8),          \
                16, 0, 0);                                                     \
        }                                                                      \
        _Pragma("unroll")                                                      \
        for (int i_ = 0; i_ < 4; ++i_) {                                       \
            __builtin_amdgcn_global_load_lds(                                  \
                (const __attribute__((address_space(1))) void*)                \
                    (wp + wsrc[i_] + (size_t)(T) * 2048),                      \
                (__attribute__((address_space(3))) void*)                      \
                    (BUF + (BB) * 16384 + 8192 + (i_ * 4 + tg) * 512 + tl8),   \
                16, 0, 0);                                                     \
        }                                                                      \
    } while (0)

    #define COMPUTE(BB) do {                                                   \
        _Pragma("unroll")                                                      \
        for (int kk_ = 0; kk_ < 4; ++kk_) {                                    \
            s16x8 a_[2], w_[2];                                                \
            _Pragma("unroll")                                                  \
            for (int m_ = 0; m_ < 2; ++m_)                                     \
                a_[m_] = *(const s16x8*)(BUF + (BB) * 16384                    \
                        + ((mw * 2 + m_) * 4 + kk_) * 512 + lane * 8);         \
            _Pragma("unroll")                                                  \
            for (int n_ = 0; n_ < 2; ++n_)                                     \
                w_[n_] = *(const s16x8*)(BUF + (BB) * 16384 + 8192             \
                        + ((nw * 2 + n_) * 4 + kk_) * 512 + lane * 8);         \
            _Pragma("unroll")                                                  \
            for (int m_ = 0; m_ < 2; ++m_)                                     \
                _Pragma("unroll")                                              \
                for (int n_ = 0; n_ < 2; ++n_)                                 \
                    acc[m_][n_] = __builtin_amdgcn_mfma_f32_32x32x16_bf16(     \
                        a_[m_], w_[n_], acc[m_][n_], 0, 0, 0);                 \
        }                                                                      \
    } while (0)

    const int nsteps = (par == 0) ? (NT / 2) : NT;

    fx16 acc[2][2];
    #pragma unroll
    for (int m = 0; m < 2; ++m)
        #pragma unroll
        for (int n = 0; n < 2; ++n)
            #pragma unroll
            for (int r = 0; r < 16; ++r) acc[m][n][r] = 0.0f;

    STAGE(0, 0);
    STAGE(1, 1);

    #pragma unroll 1
    for (int t = 0; t < nsteps; ++t) {
        if (t == nsteps - 1) {
            asm volatile("s_waitcnt vmcnt(0)" ::: "memory");
        } else {
            // retire S(t)'s 8; S(t+1)'s 8 stay in flight
            asm volatile("s_waitcnt vmcnt(8)" ::: "memory");
        }
        __builtin_amdgcn_s_barrier();          // publish buf[t&1]
        COMPUTE(t & 1);
        __builtin_amdgcn_s_barrier();          // all waves done reading buf[t&1]
        if (t + 2 < nsteps) STAGE(t + 2, t & 1);
    }
    __syncthreads();

    // ---- fused epilogue, two row-passes (p = mw of producing waves)
    const int hhl  = tid & 31;
    const int colg = hhblk * 32 + hhl;
    float bs4[4];
    #pragma unroll
    for (int g = 0; g < 4; ++g)
        bs4[g] = bsum[layer * 4096 + g * 1024 + colg];

    const float* cpar = c_buf + (size_t)(par * 2 + layer) * BH_ + colg;
    float*       cnew = c_buf + (size_t)(node * 2 + layer) * BH_ + colg;
    float*       outp = out + (size_t)(node - 1) * BH_ + colg;
    u16*         hpn  = hp + (size_t)(node * 2 + layer) * BH_;

    #pragma unroll
    for (int p = 0; p < 2; ++p) {
        __syncthreads();
        if (mw == p) {
            // C/D layout: col = lane&31, row = (r&3)+8*(r>>2)+4*(lane>>5)
            #pragma unroll
            for (int m = 0; m < 2; ++m) {
                #pragma unroll
                for (int n = 0; n < 2; ++n) {
                    const int col = (nw * 2 + n) * 32 + (lane & 31);
                    #pragma unroll
                    for (int r = 0; r < 16; ++r) {
                        const int row_l = m * 32 + 4 * (lane >> 5)
                                        + (r & 3) + 8 * (r >> 2);
                        gbuf[row_l * 129 + col] = acc[m][n][r];
                    }
                }
            }
        }
        __syncthreads();
        // gate math: 8 rows/thread-group x 32 hh
        #pragma unroll
        for (int e = 0; e < 8; ++e) {
            const int row_l = e * 8 + (tid >> 5);
            const size_t grow = (size_t)(mblk * 128 + p * 64 + row_l) * 1024;
            const float gi = gbuf[row_l * 129 + 0  * 32 + hhl] + bs4[0];
            const float gf = gbuf[row_l * 129 + 1  * 32 + hhl] + bs4[1];
            const float gg = gbuf[row_l * 129 + 2  * 32 + hhl] + bs4[2];
            const float go = gbuf[row_l * 129 + 3  * 32 + hhl] + bs4[3];
            const float cp = cpar[grow];
            const float cn = sigf(gf) * cp + sigf(gi) * tanh_f(gg);
            const float hn = sigf(go) * tanh_f(cn);
            cnew[grow] = cn;
            if (layer == 1) outp[grow] = hn;
            tbuf[row_l * 33 + hhl] = bf16_rn(hn);
        }
        __syncthreads();
        // pack h: 4 chunks (j = btl-in-pass, q = k16 half), one per wave
        {
            const int j = wv >> 1, q = wv & 1;
            const int bt   = mblk * 4 + p * 2 + j;
            const int k16h = hhblk * 2 + q;
            union { u16 s[8]; uint4 v; } pk;
            #pragma unroll
            for (int e = 0; e < 8; ++e)
                pk.s[e] = tbuf[(j * 32 + (lane & 31)) * 33
                               + q * 16 + (lane >> 5) * 8 + e];
            *(uint4*)(hpn + ((size_t)bt * 64 + k16h) * 512 + lane * 8) = pk.v;
        }
    }
    #undef STAGE
    #undef COMPUTE
}

// ---------------------------------------------------------------------------
extern "C" void kernel_launch(void* const* d_in, const int* in_sizes, int n_in,
                              void* d_out, int out_size, void* d_ws, size_t ws_size,
                              hipStream_t stream)
{
    const float* input  = (const float*)d_in[0];
    const float* bridge = (const float*)d_in[1];
    const float* Wih    = (const float*)d_in[2];
    const float* Whh    = (const float*)d_in[3];
    const float* bih    = (const float*)d_in[4];
    const float* bhh    = (const float*)d_in[5];
    float* out = (float*)d_out;

    u16* wp = (u16*)d_ws;
    u16* xp = wp + WPE;
    u16* hp = xp + XPE;
    float* c_buf = (float*)(hp + HPE);
    float* bsum  = c_buf + HPE;

    hipMemsetAsync(hp, 0, (size_t)2 * BH_ * sizeof(u16), stream);
    hipMemsetAsync(c_buf, 0, (size_t)2 * BH_ * sizeof(float), stream);

    bias_sum_k<<<32, 256, 0, stream>>>(bih, bhh, bsum);
    pack_weights<<<8192, 256, 0, stream>>>(Wih, Whh, wp);
    pack_x<<<1920, 256, 0, stream>>>(input, bridge, xp);

    // Wavefront schedule: stage T = cells (node,layer) with depth(node)+layer==T
    static const Stage stages[7] = {
        { {1},                      {0},                      {0},                      1 },
        { {1,2,5,8},                {0,1,1,1},                {1,0,0,0},                4 },
        { {2,5,8,3,6,9,12},         {1,1,1,2,5,8,8},          {1,1,1,0,0,0,0},          7 },
        { {3,6,9,12,4,7,10,13},     {2,5,8,8,3,6,9,12},       {1,1,1,1,0,0,0,0},        8 },
        { {4,7,10,13,11,14},        {3,6,9,12,10,13},         {1,1,1,1,0,0},            6 },
        { {11,14,15},               {10,13,14},               {1,1,0},                  3 },
        { {15},                     {14},                     {1},                      1 },
    };

    for (int s = 0; s < 7; ++s) {
        cell_fused<<<dim3(stages[s].cnt * 64), 256, 0, stream>>>(
            wp, xp, hp, c_buf, bsum, out, stages[s]);
    }
}